// Round 11
// baseline (761.789 us; speedup 1.0000x reference)
//
#include <hip/hip_runtime.h>
#include <hip/hip_fp16.h>
#include <math.h>

// ---------------- problem constants ----------------
static constexpr int   B_    = 4;
static constexpr int   N_    = 4096;
static constexpr int   BOX_  = 128;
static constexpr long long VOX_ = 1LL * BOX_ * BOX_ * BOX_;   // 2097152
static constexpr float EPS_IN_C  = 6.5f;
static constexpr float EPS_OUT_C = 79.0f;
static constexpr float QCONV_C   = 7046.52f;
static constexpr float KAPPA02_C = 0.8486f;
static constexpr float FOURPI_C  = 12.566370614359172f;

// ---------------- trilinear charge scatter (verified) ----------
__global__ void scatter_q_kernel(const float* __restrict__ coords,
                                 const float* __restrict__ params,
                                 const int*   __restrict__ num_atoms,
                                 float* __restrict__ q)
{
    int a = blockIdx.x * blockDim.x + threadIdx.x;
    if (a >= B_ * N_) return;
    int b = a >> 12;
    int n = a & (N_ - 1);
    if (n >= num_atoms[b]) return;

    float cx = coords[3 * a + 0];
    float cy = coords[3 * a + 1];
    float cz = coords[3 * a + 2];
    float chg = params[2 * a + 0] * QCONV_C;

    int ix0 = (int)floorf(cx), iy0 = (int)floorf(cy), iz0 = (int)floorf(cz);
    float fx = cx - (float)ix0, fy = cy - (float)iy0, fz = cz - (float)iz0;
    float wx[2] = {1.0f - fx, fx};
    float wy[2] = {1.0f - fy, fy};
    float wz[2] = {1.0f - fz, fz};

    float* qb = q + (long long)b * VOX_;
#pragma unroll
    for (int dx = 0; dx < 2; ++dx) {
        int ix = ix0 + dx;
        if ((unsigned)ix >= 128u) continue;
#pragma unroll
        for (int dy = 0; dy < 2; ++dy) {
            int iy = iy0 + dy;
            if ((unsigned)iy >= 128u) continue;
#pragma unroll
            for (int dz = 0; dz < 2; ++dz) {
                int iz = iz0 + dz;
                if ((unsigned)iz >= 128u) continue;
                atomicAdd(&qb[((long long)ix * 128 + iy) * 128 + iz],
                          chg * wx[dx] * wy[dy] * wz[dz]);
            }
        }
    }
}

// ---------------- eps gather v6: v5 compute + LDS-staged full-line stores ---
// Compute identical to round-10 v5 (wave owns z-tiles 2w/2w+1, shuffle
// weights). Store path rebuilt: per (channel, x-half) all waves stage into
// an LDS tile, then a linear copy writes fully-contiguous 512B rows (4 full
// 128B lines per 32 lanes) -- eliminates the eviction-timing-dependent
// partial-line writeback measured in rounds 9/10 (WRITE_SIZE 222418 KB,
// nondeterministic; expected exactly 131072 KB). Values bit-identical.
#define CAND_CAP 512
#define TCAP 64
#define STP 132   // staging z-pitch (padded: bank spread for ds_write)

__global__ __launch_bounds__(512)
void eps_gather_v6(const float* __restrict__ coords,
                   const float* __restrict__ params,
                   const int*   __restrict__ num_atoms,
                   float* __restrict__ eps)   // [B][4][128^3]
{
    int bid = blockIdx.x;               // B * 16 * 16 blocks
    int b   = bid >> 8;
    int txi = (bid >> 4) & 15;
    int tyi = bid & 15;
    int tx = txi << 3, ty = tyi << 3;

    __shared__ float sx[CAND_CAP], sy[CAND_CAP], sz[CAND_CAP], sr[CAND_CAP];
    __shared__ int   tlist[16][TCAP];
    __shared__ int   tcnt[16];
    __shared__ int   s_cnt;
    __shared__ float ST[32 * STP];      // [4 lx rows x 8 y][128 z padded]

    int tid = threadIdx.x;
    if (tid == 0) s_cnt = 0;
    if (tid < 16) tcnt[tid] = 0;
    __syncthreads();

    int na = num_atoms[b];
    const float* cb = coords + (size_t)b * N_ * 3;
    const float* pb = params + (size_t)b * N_ * 2;

    // ---- xy scan (once per column) ----
    float lox = (float)tx - 4.0f, hix = (float)tx + 12.5f;
    float loy = (float)ty - 4.0f, hiy = (float)ty + 12.5f;
    bool wx_ = (tx == 120), wy_ = (ty == 120);
    for (int n = tid; n < na; n += 512) {
        float cx = cb[3 * n], cy = cb[3 * n + 1], cz = cb[3 * n + 2];
        bool okx = (cx >= lox && cx < hix) || (wx_ && cx < 4.5f);
        bool oky = (cy >= loy && cy < hiy) || (wy_ && cy < 4.5f);
        if (okx && oky) {
            int slot = atomicAdd(&s_cnt, 1);
            if (slot < CAND_CAP) {
                sx[slot] = cx; sy[slot] = cy; sz[slot] = cz;
                sr[slot] = pb[2 * n + 1];
            }
        }
    }
    __syncthreads();
    int cnt = min(s_cnt, CAND_CAP);

    // ---- z bucket build (one pass) ----
    for (int i = tid; i < cnt; i += 512) {
        float cz = sz[i];
#pragma unroll
        for (int t = 0; t < 16; ++t) {
            int tz = t << 3;
            if ((cz >= (float)tz - 4.0f && cz < (float)tz + 12.5f) ||
                (tz == 120 && cz < 4.5f)) {
                int s = atomicAdd(&tcnt[t], 1);
                if (s < TCAP) tlist[t][s] = i;
            }
        }
    }
    __syncthreads();

    // ---- per-wave independent z-tiles ----
    int wid  = tid >> 6;
    int lane = tid & 63;
    int vi1  = lane >> 3;          // 0..7
    int pos1 = lane & 7;
    int ly   = lane >> 3;          // output row within tile
    int lz   = lane & 7;

    float rA0[8], rA1[8], rA2[8], rA3[8];
    float rB0[8], rB1[8], rB2[8], rB3[8];
#pragma unroll
    for (int j = 0; j < 8; ++j) {
        rA0[j] = rA1[j] = rA2[j] = rA3[j] = 0.0f;
        rB0[j] = rB1[j] = rB2[j] = rB3[j] = 0.0f;
    }

#define ACCUM_TILE(TZI, R0, R1, R2, R3)                                        \
    {                                                                          \
        int tzi = (TZI);                                                       \
        int tz  = tzi << 3;                                                    \
        int n   = min(tcnt[tzi], TCAP);                                        \
        for (int j = 0; j < n; ++j) {                                          \
            int k = tlist[tzi][j];                                             \
            float ax = sx[k], ay = sy[k], az = sz[k], r = sr[k];               \
            auto wcalc = [&](int vi, int pos) -> float {                       \
                int axis = vi / 3, var = vi - axis * 3;                        \
                float c     = (axis == 0) ? ax : (axis == 1) ? ay : az;        \
                int   torig = (axis == 0) ? tx : (axis == 1) ? ty : tz;        \
                float sig = (var == 2) ? (r + 1.0f) * 0.5f : (r + 1.4f) * 0.5f;\
                float off = (var == 0) ? 0.0f : 0.5f;                          \
                float inv2s2 = 1.0f / (2.0f * sig * sig);                      \
                int i = torig + pos;                                           \
                int base = (int)floorf(c - off) - 4;                           \
                float wv = 0.0f;                                               \
                if ((unsigned)(i - base) <= 8u) {                              \
                    float d = (float)i + off - c;                              \
                    wv = expf(-d * d * inv2s2);                                \
                } else if ((unsigned)(i - 128 - base) <= 8u) {                 \
                    float d = (float)(i - 128) + off - c;                      \
                    wv = expf(-d * d * inv2s2);                                \
                }                                                              \
                return wv;                                                     \
            };                                                                 \
            float w1 = wcalc(vi1, pos1);                                       \
            float w2 = wcalc(8, pos1);                                         \
            float yE0 = __shfl(w1, 24 + ly, 64);                               \
            float yE5 = __shfl(w1, 32 + ly, 64);                               \
            float yI5 = __shfl(w1, 40 + ly, 64);                               \
            float zE0 = __shfl(w1, 48 + lz, 64);                               \
            float zE5 = __shfl(w1, 56 + lz, 64);                               \
            float zI5 = __shfl(w2, lz, 64);                                    \
            _Pragma("unroll")                                                  \
            for (int lx = 0; lx < 8; ++lx) {                                   \
                float xE0 = __shfl(w1, lx, 64);                                \
                float xE5 = __shfl(w1, 8 + lx, 64);                            \
                float xI5 = __shfl(w1, 16 + lx, 64);                           \
                R0[lx] += xE5 * yE0 * zE0;                                     \
                R1[lx] += xE0 * yE5 * zE0;                                     \
                R2[lx] += xE0 * yE0 * zE5;                                     \
                R3[lx] += xI5 * yI5 * zI5;                                     \
            }                                                                  \
        }                                                                      \
    }

    ACCUM_TILE(wid << 1,       rA0, rA1, rA2, rA3);
    ACCUM_TILE((wid << 1) | 1, rB0, rB1, rB2, rB3);
#undef ACCUM_TILE

    // ---- staged epilogue: full 128B-line stores, timing-independent ----
    float* eb = eps + (size_t)b * 4 * VOX_;

#define STAGE_STORE(CH, RA, RB)                                                \
    _Pragma("unroll")                                                          \
    for (int half = 0; half < 2; ++half) {                                     \
        __syncthreads();               /* staging buffer free */               \
        _Pragma("unroll")                                                      \
        for (int l4 = 0; l4 < 4; ++l4) {                                       \
            int lxs = half * 4 + l4;                                           \
            float va = RA[lxs], vb = RB[lxs];                                  \
            va = EPS_OUT_C + (EPS_IN_C - EPS_OUT_C) * fminf(fmaxf(va, 0.0f), 1.0f); \
            vb = EPS_OUT_C + (EPS_IN_C - EPS_OUT_C) * fminf(fmaxf(vb, 0.0f), 1.0f); \
            int row = l4 * 8 + ly;                                             \
            ST[row * STP + (wid << 4) + lz]     = va;                          \
            ST[row * STP + (wid << 4) + 8 + lz] = vb;                          \
        }                                                                      \
        __syncthreads();                                                       \
        _Pragma("unroll")                                                      \
        for (int it = 0; it < 2; ++it) {                                       \
            int idx = it * 512 + tid;     /* 0..1023 */                        \
            int row = idx >> 5;           /* 0..31 */                          \
            int k   = idx & 31;                                                \
            float4 v = *reinterpret_cast<const float4*>(&ST[row * STP + 4 * k]); \
            int lxo = half * 4 + (row >> 3);                                   \
            int yy  = row & 7;                                                 \
            size_t sp = (size_t)(CH) * (size_t)VOX_ +                          \
                        ((size_t)(tx + lxo) * 128 + (size_t)(ty + yy)) * 128 + \
                        (size_t)(4 * k);                                       \
            *reinterpret_cast<float4*>(eb + sp) = v;                           \
        }                                                                      \
    }

    STAGE_STORE(0, rA0, rB0);
    STAGE_STORE(1, rA1, rB1);
    STAGE_STORE(2, rA2, rB2);
    STAGE_STORE(3, rA3, rB3);
#undef STAGE_STORE
}

// ---------------- coefficient pack v4: 4 z-voxels/thread, vectorized --------
// Folds Jacobi sweep 1 (phi_0 == 0): phi1 = float(half(4*pi*q*rcp)).
__global__ void coef_pack4(const float* __restrict__ eps,
                           const float* __restrict__ q,
                           uint4* __restrict__ coef,
                           float* __restrict__ phi1)
{
    int tid = blockIdx.x * blockDim.x + threadIdx.x;   // 0 .. B*VOX/4-1
    size_t g4 = (size_t)tid * 4;
    int b  = (int)(g4 >> 21);
    size_t sp = g4 & (size_t)(VOX_ - 1);
    int x  = (int)(sp >> 14);
    int y  = (int)((sp >> 7) & 127);
    int z4 = (int)(sp & 127);          // 0,4,...,124

    const float* E = eps + (size_t)b * 4 * (size_t)VOX_;
    float4 ex4 = *reinterpret_cast<const float4*>(E + sp);
    float4 ey4 = *reinterpret_cast<const float4*>(E + sp + (size_t)VOX_);
    float4 ez4 = *reinterpret_cast<const float4*>(E + sp + (size_t)VOX_ * 2);
    float4 ek4 = *reinterpret_cast<const float4*>(E + sp + (size_t)VOX_ * 3);
    float4 eo  = make_float4(EPS_OUT_C, EPS_OUT_C, EPS_OUT_C, EPS_OUT_C);
    float4 exm4 = (x > 0) ? *reinterpret_cast<const float4*>(E + sp - 16384) : eo;
    float4 eym4 = (y > 0) ? *reinterpret_cast<const float4*>(E + sp + (size_t)VOX_ - 128) : eo;
    float ezm0  = (z4 > 0) ? E[sp + (size_t)VOX_ * 2 - 1] : EPS_OUT_C;
    float4 q4  = *reinterpret_cast<const float4*>(q + g4);

    float exA[4]  = {ex4.x, ex4.y, ex4.z, ex4.w};
    float eyA[4]  = {ey4.x, ey4.y, ey4.z, ey4.w};
    float ezA[4]  = {ez4.x, ez4.y, ez4.z, ez4.w};
    float ekA[4]  = {ek4.x, ek4.y, ek4.z, ek4.w};
    float exmA[4] = {exm4.x, exm4.y, exm4.z, exm4.w};
    float eymA[4] = {eym4.x, eym4.y, eym4.z, eym4.w};
    float ezmA[4] = {ezm0, ez4.x, ez4.y, ez4.z};
    float qA[4]   = {q4.x, q4.y, q4.z, q4.w};

    float ph[4];
#pragma unroll
    for (int j = 0; j < 4; ++j) {
        float lam = (ekA[j] - EPS_IN_C) / (EPS_OUT_C - EPS_IN_C);
        lam = fminf(fmaxf(lam, 0.0f), 1.0f);
        float denom = exA[j] + exmA[j] + eyA[j] + eymA[j] + ezA[j] + ezmA[j]
                    + KAPPA02_C * lam;
        float rcp = 1.0f / denom;

        __half2 h01 = __floats2half2_rn(exA[j] * rcp, exmA[j] * rcp);
        __half2 h23 = __floats2half2_rn(eyA[j] * rcp, eymA[j] * rcp);
        __half2 h45 = __floats2half2_rn(ezA[j] * rcp, ezmA[j] * rcp);
        __half2 h67 = __floats2half2_rn(FOURPI_C * qA[j] * rcp, 0.0f);
        uint4 u;
        u.x = *(unsigned int*)&h01;
        u.y = *(unsigned int*)&h23;
        u.z = *(unsigned int*)&h45;
        u.w = *(unsigned int*)&h67;
        coef[g4 + j] = u;
        ph[j] = __half22float2(h67).x;
    }
    *reinterpret_cast<float4*>(phi1 + g4) = make_float4(ph[0], ph[1], ph[2], ph[3]);
}

// ---------------- fused 2-step Jacobi, prefetched (T14, verified round-6) ---
#define TY 8
#define TZ 32
#define RY (TY + 2)    // 10
#define RZ (TZ + 2)    // 34
#define PYD (TY + 4)   // 12
#define PZD (TZ + 4)   // 36
#define SEG 16         // 2048 blocks = 8/CU

__global__ __launch_bounds__(256)
void jacobi_f2p(const uint4* __restrict__ coef,
                const float* __restrict__ pin,
                float* __restrict__ pout)
{
    int bid = blockIdx.x;                 // 2048 blocks
    int xs = bid & 7;
    int zt = (bid >> 3) & 3;
    int yt = (bid >> 5) & 15;
    int b  = bid >> 9;
    int x_lo = xs * SEG, x_hi = x_lo + SEG - 1;
    int y0 = yt * TY, z0 = zt * TZ;

    __shared__ float P[3][PYD * PZD];     // phi_in slices x, x-1, x-2
    __shared__ float S[3][RY * RZ];       // step-1 phi slices

    int tid = threadIdx.x;
    int oy = tid >> 5, oz = tid & 31;

    const uint4* cb = coef + (size_t)b * VOX_;
    const float* pb = pin  + (size_t)b * VOX_;
    float*       ob = pout + (size_t)b * VOX_;

    // ---- static per-thread geometry ----
    int e1_i  = (oy + 1) * RZ + (oz + 1);
    int g1y = y0 + oy, g1z = z0 + oz;
    int e1_off = g1y * 128 + g1z;
    int e1_p0 = (oy + 2) * PZD + (oz + 2);
    bool has2 = (tid < 84);
    int e2_ry = 0, e2_rz = 0;
    if (tid < 34)      { e2_ry = 0;      e2_rz = tid; }
    else if (tid < 68) { e2_ry = RY - 1; e2_rz = tid - 34; }
    else if (tid < 84) { int t2 = tid - 68; e2_ry = 1 + (t2 >> 1); e2_rz = (t2 & 1) * (RZ - 1); }
    int e2_i = e2_ry * RZ + e2_rz;
    int g2y = y0 - 1 + e2_ry, g2z = z0 - 1 + e2_rz;
    bool e2_ok = ((unsigned)g2y < 128u) && ((unsigned)g2z < 128u);
    int e2_off = min(max(g2y, 0), 127) * 128 + min(max(g2z, 0), 127);
    int e2_p0 = (e2_ry + 1) * PZD + (e2_rz + 1);
    int p1_py = tid / PZD, p1_pz = tid - p1_py * PZD;
    int p1y = y0 - 2 + p1_py, p1z = z0 - 2 + p1_pz;
    bool p1_ok = ((unsigned)p1y < 128u) && ((unsigned)p1z < 128u);
    int p1_off = min(max(p1y, 0), 127) * 128 + min(max(p1z, 0), 127);
    int p2i = tid + 256;
    bool hasP2 = (p2i < PYD * PZD);
    int p2_py = p2i / PZD, p2_pz = p2i - p2_py * PZD;
    int p2y = y0 - 2 + p2_py, p2z = z0 - 2 + p2_pz;
    bool p2_ok = hasP2 && ((unsigned)p2y < 128u) && ((unsigned)p2z < 128u);
    int p2_off = min(max(p2y, 0), 127) * 128 + min(max(p2z, 0), 127);

    const float* ps0 = pb + (size_t)min(max(x_lo - 2, 0), 127) * 16384;
    float pfA = ps0[p1_off];
    float pfB = hasP2 ? ps0[p2_off] : 0.0f;
    uint4 cf1 = make_uint4(0u, 0u, 0u, 0u);
    uint4 cf2 = make_uint4(0u, 0u, 0u, 0u);
    uint4 hold = make_uint4(0u, 0u, 0u, 0u);
    uint4 cnew = make_uint4(0u, 0u, 0u, 0u);

    for (int x = x_lo - 2; x <= x_hi + 2; ++x) {
        int s0 = (x + 3) % 3;             // slot(x)
        int s1 = (x + 2) % 3;             // slot(x-1)
        int s2 = (x + 1) % 3;             // slot(x-2)
        bool xin = (x >= 0 && x < 128);

        // ---- W: commit prefetched phi(x) to P[s0] ----
        P[s0][tid] = (xin && p1_ok) ? pfA : 0.0f;
        if (hasP2) P[s0][p2i] = (xin && p2_ok) ? pfB : 0.0f;
        asm volatile("s_waitcnt lgkmcnt(0)" ::: "memory");
        __builtin_amdgcn_s_barrier();

        // ---- I: issue phi(x+1) prefetch (consumed next W) ----
        if (x < x_hi + 2) {
            const float* ps = pb + (size_t)min(max(x + 1, 0), 127) * 16384;
            pfA = ps[p1_off];
            if (hasP2) pfB = ps[p2_off];
        }

        // ---- B: compute S1(x-1) from coef regs + P ----
        if (x >= x_lo) {
            int k = x - 1;
            bool kin = ((unsigned)k < 128u);
            {
                float v = 0.0f;
                if (kin) {
                    const __half2* h = reinterpret_cast<const __half2*>(&cf1);
                    float2 a01 = __half22float2(h[0]);
                    float2 a23 = __half22float2(h[1]);
                    float2 a45 = __half22float2(h[2]);
                    float2 a67 = __half22float2(h[3]);
                    v = a01.x * P[s0][e1_p0]
                      + a01.y * P[s2][e1_p0]
                      + a23.x * P[s1][e1_p0 + PZD]
                      + a23.y * P[s1][e1_p0 - PZD]
                      + a45.x * P[s1][e1_p0 + 1]
                      + a45.y * P[s1][e1_p0 - 1]
                      + a67.x;
                }
                S[s1][e1_i] = v;
                cnew = cf1;
            }
            if (has2) {
                float v = 0.0f;
                if (kin && e2_ok) {
                    const __half2* h = reinterpret_cast<const __half2*>(&cf2);
                    float2 a01 = __half22float2(h[0]);
                    float2 a23 = __half22float2(h[1]);
                    float2 a45 = __half22float2(h[2]);
                    float2 a67 = __half22float2(h[3]);
                    v = a01.x * P[s0][e2_p0]
                      + a01.y * P[s2][e2_p0]
                      + a23.x * P[s1][e2_p0 + PZD]
                      + a23.y * P[s1][e2_p0 - PZD]
                      + a45.x * P[s1][e2_p0 + 1]
                      + a45.y * P[s1][e2_p0 - 1]
                      + a67.x;
                }
                S[s1][e2_i] = v;
            }
        }
        if (x >= x_lo - 1 && x <= x_hi + 1) {
            const uint4* cs = cb + (size_t)min(max(x, 0), 127) * 16384;
            cf1 = cs[e1_off];
            if (has2) cf2 = cs[e2_off];
        }
        asm volatile("s_waitcnt lgkmcnt(0)" ::: "memory");
        __builtin_amdgcn_s_barrier();

        // ---- C: output xo = x-2 from reg coef + S ----
        int xo = x - 2;
        if (xo >= x_lo) {
            const __half2* h = reinterpret_cast<const __half2*>(&hold);
            float2 a01 = __half22float2(h[0]);
            float2 a23 = __half22float2(h[1]);
            float2 a45 = __half22float2(h[2]);
            float2 a67 = __half22float2(h[3]);
            int j0 = e1_i;
            float out = a01.x * S[s1][j0]
                      + a01.y * S[s0][j0]
                      + a23.x * S[s2][j0 + RZ]
                      + a23.y * S[s2][j0 - RZ]
                      + a45.x * S[s2][j0 + 1]
                      + a45.y * S[s2][j0 - 1]
                      + a67.x;
            ob[(size_t)xo * 16384 + e1_off] = out;
        }
        hold = cnew;
    }
}

// ---------------- Jacobi sweep v3: 4 z-voxels/thread, fp16 coefs (verified) -
__global__ void jacobi_v3(const uint4* __restrict__ coef,
                          const float* __restrict__ pin,
                          float* __restrict__ pout)
{
    int tid = blockIdx.x * blockDim.x + threadIdx.x;   // 0 .. B*VOX/4-1
    size_t g4 = (size_t)tid * 4;
    int z4 = (int)(g4 & 127);          // 0,4,...,124
    int y  = (int)((g4 >> 7) & 127);
    int x  = (int)((g4 >> 14) & 127);

    float4 pcv = *reinterpret_cast<const float4*>(pin + g4);
    float4 z4v = make_float4(0.f, 0.f, 0.f, 0.f);
    float4 pxpv = (x < 127) ? *reinterpret_cast<const float4*>(pin + g4 + 16384) : z4v;
    float4 pxmv = (x > 0)   ? *reinterpret_cast<const float4*>(pin + g4 - 16384) : z4v;
    float4 pypv = (y < 127) ? *reinterpret_cast<const float4*>(pin + g4 + 128)   : z4v;
    float4 pymv = (y > 0)   ? *reinterpret_cast<const float4*>(pin + g4 - 128)   : z4v;
    float zpE = (z4 < 124) ? pin[g4 + 4] : 0.0f;
    float zmE = (z4 > 0)   ? pin[g4 - 1] : 0.0f;

    float pxp[4] = {pxpv.x, pxpv.y, pxpv.z, pxpv.w};
    float pxm[4] = {pxmv.x, pxmv.y, pxmv.z, pxmv.w};
    float pyp[4] = {pypv.x, pypv.y, pypv.z, pypv.w};
    float pym[4] = {pymv.x, pymv.y, pymv.z, pymv.w};
    float pzp[4] = {pcv.y, pcv.z, pcv.w, zpE};
    float pzm[4] = {zmE, pcv.x, pcv.y, pcv.z};

    float out[4];
#pragma unroll
    for (int j = 0; j < 4; ++j) {
        uint4 cu = coef[g4 + j];
        const __half2* h = reinterpret_cast<const __half2*>(&cu);
        float2 a01 = __half22float2(h[0]);
        float2 a23 = __half22float2(h[1]);
        float2 a45 = __half22float2(h[2]);
        float2 a67 = __half22float2(h[3]);
        out[j] = a01.x * pxp[j] + a01.y * pxm[j]
               + a23.x * pyp[j] + a23.y * pym[j]
               + a45.x * pzp[j] + a45.y * pzm[j]
               + a67.x;
    }
    *reinterpret_cast<float4*>(pout + g4) = make_float4(out[0], out[1], out[2], out[3]);
}

// ---------------- Jacobi sweep v2 (fallback path, verified) ----------------
__global__ void jacobi_v2(const float* __restrict__ eps,
                          const float* __restrict__ q,
                          const float* __restrict__ pin,
                          float* __restrict__ pout)
{
    int bxy = blockIdx.x;
    int b = bxy >> 14;
    int x = (bxy >> 7) & 127;
    int y = bxy & 127;
    int z = threadIdx.x;

    size_t sp = ((size_t)x * 128 + y) * 128 + z;
    size_t g  = (size_t)b * (size_t)VOX_ + sp;
    const float* E = eps + (size_t)b * 4 * (size_t)VOX_;

    float ex = E[sp];
    float ey = E[sp + (size_t)VOX_];
    float ez = E[sp + (size_t)VOX_ * 2];
    float ek = E[sp + (size_t)VOX_ * 3];
    float exm = (x > 0) ? E[sp - 16384]                 : EPS_OUT_C;
    float eym = (y > 0) ? E[sp + (size_t)VOX_ - 128]    : EPS_OUT_C;
    float ezm = (z > 0) ? E[sp + (size_t)VOX_ * 2 - 1]  : EPS_OUT_C;

    float lam = (ek - EPS_IN_C) / (EPS_OUT_C - EPS_IN_C);
    lam = fminf(fmaxf(lam, 0.0f), 1.0f);
    float denom = ex + exm + ey + eym + ez + ezm + KAPPA02_C * lam;

    float pxp = (x < 127) ? pin[g + 16384] : 0.0f;
    float pxm = (x > 0)   ? pin[g - 16384] : 0.0f;
    float pyp = (y < 127) ? pin[g + 128]   : 0.0f;
    float pym = (y > 0)   ? pin[g - 128]   : 0.0f;
    float pzp = (z < 127) ? pin[g + 1]     : 0.0f;
    float pzm = (z > 0)   ? pin[g - 1]     : 0.0f;

    float num = ex * pxp + exm * pxm + ey * pyp + eym * pym
              + ez * pzp + ezm * pzm + FOURPI_C * q[g];
    pout[g] = num / denom;
}

// ---------------- launch ----------------
extern "C" void kernel_launch(void* const* d_in, const int* in_sizes, int n_in,
                              void* d_out, int out_size, void* d_ws, size_t ws_size,
                              hipStream_t stream)
{
    const float* coords    = (const float*)d_in[0];
    const float* params    = (const float*)d_in[1];
    const int*   num_atoms = (const int*)d_in[2];

    float* q   = (float*)d_out;                       // [B][128^3]
    float* eps = q + (size_t)B_ * VOX_;               // [B][4][128^3]
    float* phi = eps + (size_t)B_ * 4 * VOX_;         // [B][128^3]

    hipMemsetAsync(q, 0, (size_t)B_ * VOX_ * sizeof(float), stream);

    scatter_q_kernel<<<(B_ * N_ + 255) / 256, 256, 0, stream>>>(coords, params, num_atoms, q);
    eps_gather_v6<<<B_ * 16 * 16, 512, 0, stream>>>(coords, params, num_atoms, eps);

    size_t coefBytes = (size_t)B_ * VOX_ * sizeof(uint4);              // 134 MB
    size_t need = coefBytes + (size_t)B_ * VOX_ * sizeof(float);       // +33.5 MB

    if (ws_size >= need) {
        uint4* coefA = (uint4*)d_ws;
        float* tmp   = (float*)((char*)d_ws + coefBytes);
        // sweep 1 folded into coef_pack4 (phi_0 == 0): phi1 -> phi
        coef_pack4<<<(int)(B_ * VOX_ / 4 / 256), 256, 0, stream>>>(eps, q, coefA, phi);
        const float* cur = phi;
        for (int it = 1; it <= 9; ++it) {           // 9 fused = sweeps 2..19
            float* dst = (it & 1) ? tmp : phi;      // it=9 (odd) -> tmp
            jacobi_f2p<<<B_ * 16 * 4 * 8, 256, 0, stream>>>(coefA, cur, dst);
            cur = dst;
        }
        // sweep 20: single v3 sweep tmp -> phi (d_out)
        jacobi_v3<<<(int)(B_ * VOX_ / 4 / 256), 256, 0, stream>>>(coefA, cur, phi);
    } else {
        hipMemsetAsync(phi, 0, (size_t)B_ * VOX_ * sizeof(float), stream);
        float* tmp = (float*)d_ws;
        int jb = B_ * 128 * 128;
        const float* cur = phi;
        for (int it = 1; it <= 20; ++it) {
            float* dst = (it & 1) ? tmp : phi;
            jacobi_v2<<<jb, 128, 0, stream>>>(eps, q, cur, dst);
            cur = dst;
        }
    }
}

// Round 12
// 724.385 us; speedup vs baseline: 1.0516x; 1.0516x over previous
//
#include <hip/hip_runtime.h>
#include <hip/hip_fp16.h>
#include <math.h>

// ---------------- problem constants ----------------
static constexpr int   B_    = 4;
static constexpr int   N_    = 4096;
static constexpr int   BOX_  = 128;
static constexpr long long VOX_ = 1LL * BOX_ * BOX_ * BOX_;   // 2097152
static constexpr float EPS_IN_C  = 6.5f;
static constexpr float EPS_OUT_C = 79.0f;
static constexpr float QCONV_C   = 7046.52f;
static constexpr float KAPPA02_C = 0.8486f;
static constexpr float FOURPI_C  = 12.566370614359172f;

// ---------------- trilinear charge scatter (verified) ----------
__global__ void scatter_q_kernel(const float* __restrict__ coords,
                                 const float* __restrict__ params,
                                 const int*   __restrict__ num_atoms,
                                 float* __restrict__ q)
{
    int a = blockIdx.x * blockDim.x + threadIdx.x;
    if (a >= B_ * N_) return;
    int b = a >> 12;
    int n = a & (N_ - 1);
    if (n >= num_atoms[b]) return;

    float cx = coords[3 * a + 0];
    float cy = coords[3 * a + 1];
    float cz = coords[3 * a + 2];
    float chg = params[2 * a + 0] * QCONV_C;

    int ix0 = (int)floorf(cx), iy0 = (int)floorf(cy), iz0 = (int)floorf(cz);
    float fx = cx - (float)ix0, fy = cy - (float)iy0, fz = cz - (float)iz0;
    float wx[2] = {1.0f - fx, fx};
    float wy[2] = {1.0f - fy, fy};
    float wz[2] = {1.0f - fz, fz};

    float* qb = q + (long long)b * VOX_;
#pragma unroll
    for (int dx = 0; dx < 2; ++dx) {
        int ix = ix0 + dx;
        if ((unsigned)ix >= 128u) continue;
#pragma unroll
        for (int dy = 0; dy < 2; ++dy) {
            int iy = iy0 + dy;
            if ((unsigned)iy >= 128u) continue;
#pragma unroll
            for (int dz = 0; dz < 2; ++dz) {
                int iz = iz0 + dz;
                if ((unsigned)iz >= 128u) continue;
                atomicAdd(&qb[((long long)ix * 128 + iy) * 128 + iz],
                          chg * wx[dx] * wy[dy] * wz[dz]);
            }
        }
    }
}

// ---------------- eps gather v3 (round-8 verified): z-column blocks ---------
// One block per (b, tx, ty): scans atoms ONCE with the exact x/y window test
// (c in [t-4, t+12.5) union wrap c<4.5 for t=120), then per z-tile applies
// the z test in-LDS and runs the verified Phase A/B.
#define CAND_CAP 512
#define CHUNK 32

__global__ __launch_bounds__(512)
void eps_gather_v3(const float* __restrict__ coords,
                   const float* __restrict__ params,
                   const int*   __restrict__ num_atoms,
                   float* __restrict__ eps)   // [B][4][128^3]
{
    int bid = blockIdx.x;               // B * 16 * 16 blocks
    int b   = bid >> 8;
    int txi = (bid >> 4) & 15;
    int tyi = bid & 15;
    int tx = txi << 3, ty = tyi << 3;

    __shared__ float sx[CAND_CAP], sy[CAND_CAP], sz[CAND_CAP], sr[CAND_CAP];
    __shared__ float wts[CHUNK][9][8];   // [atom][axis*3+variant][tile pos]
    __shared__ int  fidx[CAND_CAP];      // per-z-tile filtered candidate idx
    __shared__ int  s_cnt, s_fcnt;
    if (threadIdx.x == 0) s_cnt = 0;
    __syncthreads();

    int na = num_atoms[b];
    const float* cb = coords + (size_t)b * N_ * 3;
    const float* pb = params + (size_t)b * N_ * 2;

    // ---- xy scan (once per column) ----
    float lox = (float)tx - 4.0f, hix = (float)tx + 12.5f;
    float loy = (float)ty - 4.0f, hiy = (float)ty + 12.5f;
    bool wx_ = (tx == 120), wy_ = (ty == 120);
    for (int n = threadIdx.x; n < na; n += 512) {
        float cx = cb[3 * n], cy = cb[3 * n + 1], cz = cb[3 * n + 2];
        bool okx = (cx >= lox && cx < hix) || (wx_ && cx < 4.5f);
        bool oky = (cy >= loy && cy < hiy) || (wy_ && cy < 4.5f);
        if (okx && oky) {
            int slot = atomicAdd(&s_cnt, 1);
            if (slot < CAND_CAP) {
                sx[slot] = cx; sy[slot] = cy; sz[slot] = cz;
                sr[slot] = pb[2 * n + 1];
            }
        }
    }
    __syncthreads();
    int cnt = min(s_cnt, CAND_CAP);

    int lz = threadIdx.x & 7;
    int ly = (threadIdx.x >> 3) & 7;
    int lx = threadIdx.x >> 6;

    float* eb = eps + (size_t)b * 4 * VOX_;

    for (int tzi = 0; tzi < 16; ++tzi) {
        int tz = tzi << 3;

        // ---- z filter into fidx ----
        __syncthreads();                 // prior Phase B / fidx reads done
        if (threadIdx.x == 0) s_fcnt = 0;
        __syncthreads();
        {
            float loz = (float)tz - 4.0f, hiz = (float)tz + 12.5f;
            bool wz_ = (tz == 120);
            for (int i = threadIdx.x; i < cnt; i += 512) {
                float cz = sz[i];
                if ((cz >= loz && cz < hiz) || (wz_ && cz < 4.5f)) {
                    int s = atomicAdd(&s_fcnt, 1);
                    fidx[s] = i;
                }
            }
        }
        __syncthreads();
        int fcnt = s_fcnt;

        float r0 = 0.0f, r1 = 0.0f, r2 = 0.0f, r3 = 0.0f;

        for (int k0 = 0; k0 < fcnt; k0 += CHUNK) {
            int nC = min(CHUNK, fcnt - k0);
            __syncthreads();             // protect wts reuse across chunks
            // Phase A: per-atom separable axis weights (72 expf per atom)
            for (int w = threadIdx.x; w < nC * 72; w += 512) {
                int ka  = w / 72;
                int rem = w - ka * 72;
                int vi  = rem >> 3;      // 0..8 = axis*3 + variant
                int pos = rem & 7;
                int axis = vi / 3, var = vi - axis * 3;
                int k = fidx[k0 + ka];
                float c     = (axis == 0) ? sx[k] : (axis == 1) ? sy[k] : sz[k];
                int   torig = (axis == 0) ? tx    : (axis == 1) ? ty    : tz;
                float r = sr[k];
                float sig = (var == 2) ? (r + 1.0f) * 0.5f : (r + 1.4f) * 0.5f;
                float off = (var == 0) ? 0.0f : 0.5f;
                float inv2s2 = 1.0f / (2.0f * sig * sig);
                int i = torig + pos;
                int base = (int)floorf(c - off) - 4;    // window [base, base+8]
                float wv = 0.0f;
                if ((unsigned)(i - base) <= 8u) {
                    float d = (float)i + off - c;
                    wv = expf(-d * d * inv2s2);
                } else if ((unsigned)(i - 128 - base) <= 8u) {   // JAX wrap
                    float d = (float)(i - 128) + off - c;
                    wv = expf(-d * d * inv2s2);
                }
                wts[ka][vi][pos] = wv;
            }
            __syncthreads();
            // Phase B: accumulate channels from separable products
            for (int ka = 0; ka < nC; ++ka) {
                float xE0 = wts[ka][0][lx], xE5 = wts[ka][1][lx], xI5 = wts[ka][2][lx];
                float yE0 = wts[ka][3][ly], yE5 = wts[ka][4][ly], yI5 = wts[ka][5][ly];
                float zE0 = wts[ka][6][lz], zE5 = wts[ka][7][lz], zI5 = wts[ka][8][lz];
                r0 += xE5 * yE0 * zE0;     // c0: off (.5,0,0)  sigE
                r1 += xE0 * yE5 * zE0;     // c1: off (0,.5,0)  sigE
                r2 += xE0 * yE0 * zE5;     // c2: off (0,0,.5)  sigE
                r3 += xI5 * yI5 * zI5;     // c3: off (.5,.5,.5) sigI
            }
        }

        int ix = tx + lx, iy = ty + ly, iz = tz + lz;
        size_t sp = ((size_t)ix * 128 + iy) * 128 + iz;
        eb[sp]                    = EPS_OUT_C + (EPS_IN_C - EPS_OUT_C) * fminf(fmaxf(r0, 0.0f), 1.0f);
        eb[sp + (size_t)VOX_]     = EPS_OUT_C + (EPS_IN_C - EPS_OUT_C) * fminf(fmaxf(r1, 0.0f), 1.0f);
        eb[sp + (size_t)VOX_ * 2] = EPS_OUT_C + (EPS_IN_C - EPS_OUT_C) * fminf(fmaxf(r2, 0.0f), 1.0f);
        eb[sp + (size_t)VOX_ * 3] = EPS_OUT_C + (EPS_IN_C - EPS_OUT_C) * fminf(fmaxf(r3, 0.0f), 1.0f);
    }
}

// ---------------- coefficient pack v4: 4 z-voxels/thread, vectorized --------
// Folds Jacobi sweep 1 (phi_0 == 0): phi1 = float(half(4*pi*q*rcp)).
__global__ void coef_pack4(const float* __restrict__ eps,
                           const float* __restrict__ q,
                           uint4* __restrict__ coef,
                           float* __restrict__ phi1)
{
    int tid = blockIdx.x * blockDim.x + threadIdx.x;   // 0 .. B*VOX/4-1
    size_t g4 = (size_t)tid * 4;
    int b  = (int)(g4 >> 21);
    size_t sp = g4 & (size_t)(VOX_ - 1);
    int x  = (int)(sp >> 14);
    int y  = (int)((sp >> 7) & 127);
    int z4 = (int)(sp & 127);          // 0,4,...,124

    const float* E = eps + (size_t)b * 4 * (size_t)VOX_;
    float4 ex4 = *reinterpret_cast<const float4*>(E + sp);
    float4 ey4 = *reinterpret_cast<const float4*>(E + sp + (size_t)VOX_);
    float4 ez4 = *reinterpret_cast<const float4*>(E + sp + (size_t)VOX_ * 2);
    float4 ek4 = *reinterpret_cast<const float4*>(E + sp + (size_t)VOX_ * 3);
    float4 eo  = make_float4(EPS_OUT_C, EPS_OUT_C, EPS_OUT_C, EPS_OUT_C);
    float4 exm4 = (x > 0) ? *reinterpret_cast<const float4*>(E + sp - 16384) : eo;
    float4 eym4 = (y > 0) ? *reinterpret_cast<const float4*>(E + sp + (size_t)VOX_ - 128) : eo;
    float ezm0  = (z4 > 0) ? E[sp + (size_t)VOX_ * 2 - 1] : EPS_OUT_C;
    float4 q4  = *reinterpret_cast<const float4*>(q + g4);

    float exA[4]  = {ex4.x, ex4.y, ex4.z, ex4.w};
    float eyA[4]  = {ey4.x, ey4.y, ey4.z, ey4.w};
    float ezA[4]  = {ez4.x, ez4.y, ez4.z, ez4.w};
    float ekA[4]  = {ek4.x, ek4.y, ek4.z, ek4.w};
    float exmA[4] = {exm4.x, exm4.y, exm4.z, exm4.w};
    float eymA[4] = {eym4.x, eym4.y, eym4.z, eym4.w};
    float ezmA[4] = {ezm0, ez4.x, ez4.y, ez4.z};
    float qA[4]   = {q4.x, q4.y, q4.z, q4.w};

    float ph[4];
#pragma unroll
    for (int j = 0; j < 4; ++j) {
        float lam = (ekA[j] - EPS_IN_C) / (EPS_OUT_C - EPS_IN_C);
        lam = fminf(fmaxf(lam, 0.0f), 1.0f);
        float denom = exA[j] + exmA[j] + eyA[j] + eymA[j] + ezA[j] + ezmA[j]
                    + KAPPA02_C * lam;
        float rcp = 1.0f / denom;

        __half2 h01 = __floats2half2_rn(exA[j] * rcp, exmA[j] * rcp);
        __half2 h23 = __floats2half2_rn(eyA[j] * rcp, eymA[j] * rcp);
        __half2 h45 = __floats2half2_rn(ezA[j] * rcp, ezmA[j] * rcp);
        __half2 h67 = __floats2half2_rn(FOURPI_C * qA[j] * rcp, 0.0f);
        uint4 u;
        u.x = *(unsigned int*)&h01;
        u.y = *(unsigned int*)&h23;
        u.z = *(unsigned int*)&h45;
        u.w = *(unsigned int*)&h67;
        coef[g4 + j] = u;
        ph[j] = __half22float2(h67).x;
    }
    *reinterpret_cast<float4*>(phi1 + g4) = make_float4(ph[0], ph[1], ph[2], ph[3]);
}

// ---------------- fused 2-step Jacobi, prefetched, 16x32 tile (round 12) ----
// Identical phase structure / barriers / FP order to the round-6-verified
// f2p; only the tile is widened 8x32 -> 16x32 (512 threads) to cut the
// y/z halo share: coef 23.9 -> 21.5 B/voxel, phi 7.6 -> 6.3.
// Occupancy preserved: 1024 blocks = 4/CU x 8 waves = 32 waves/CU.
#define TY 16
#define TZ 32
#define RY (TY + 2)    // 18
#define RZ (TZ + 2)    // 34
#define PYD (TY + 4)   // 20
#define PZD (TZ + 4)   // 36
#define SEG 16

__global__ __launch_bounds__(512)
void jacobi_f2p(const uint4* __restrict__ coef,
                const float* __restrict__ pin,
                float* __restrict__ pout)
{
    int bid = blockIdx.x;                 // 1024 blocks
    int xs = bid & 7;
    int zt = (bid >> 3) & 3;
    int yt = (bid >> 5) & 7;
    int b  = bid >> 8;
    int x_lo = xs * SEG, x_hi = x_lo + SEG - 1;
    int y0 = yt * TY, z0 = zt * TZ;

    __shared__ float P[3][PYD * PZD];     // phi_in slices x, x-1, x-2 (720)
    __shared__ float S[3][RY * RZ];       // step-1 phi slices (612)

    int tid = threadIdx.x;
    int oy = tid >> 5, oz = tid & 31;     // oy 0..15, oz 0..31

    const uint4* cb = coef + (size_t)b * VOX_;
    const float* pb = pin  + (size_t)b * VOX_;
    float*       ob = pout + (size_t)b * VOX_;

    // ---- static per-thread geometry ----
    int e1_i  = (oy + 1) * RZ + (oz + 1);
    int g1y = y0 + oy, g1z = z0 + oz;
    int e1_off = g1y * 128 + g1z;
    int e1_p0 = (oy + 2) * PZD + (oz + 2);
    // halo: ring minus 16x32 center = 2*34 + 2*16 = 100 entries, tids 0..99
    bool has2 = (tid < 100);
    int e2_ry = 0, e2_rz = 0;
    if (tid < 34)       { e2_ry = 0;      e2_rz = tid; }
    else if (tid < 68)  { e2_ry = RY - 1; e2_rz = tid - 34; }
    else if (tid < 100) { int t2 = tid - 68; e2_ry = 1 + (t2 >> 1); e2_rz = (t2 & 1) * (RZ - 1); }
    int e2_i = e2_ry * RZ + e2_rz;
    int g2y = y0 - 1 + e2_ry, g2z = z0 - 1 + e2_rz;
    bool e2_ok = ((unsigned)g2y < 128u) && ((unsigned)g2z < 128u);
    int e2_off = min(max(g2y, 0), 127) * 128 + min(max(g2z, 0), 127);
    int e2_p0 = (e2_ry + 1) * PZD + (e2_rz + 1);
    // phi tile entries: tid and tid+512 (tid < 208)
    int p1_py = tid / PZD, p1_pz = tid - p1_py * PZD;
    int p1y = y0 - 2 + p1_py, p1z = z0 - 2 + p1_pz;
    bool p1_ok = ((unsigned)p1y < 128u) && ((unsigned)p1z < 128u);
    int p1_off = min(max(p1y, 0), 127) * 128 + min(max(p1z, 0), 127);
    int p2i = tid + 512;
    bool hasP2 = (p2i < PYD * PZD);
    int p2_py = p2i / PZD, p2_pz = p2i - p2_py * PZD;
    int p2y = y0 - 2 + p2_py, p2z = z0 - 2 + p2_pz;
    bool p2_ok = hasP2 && ((unsigned)p2y < 128u) && ((unsigned)p2z < 128u);
    int p2_off = min(max(p2y, 0), 127) * 128 + min(max(p2z, 0), 127);

    const float* ps0 = pb + (size_t)min(max(x_lo - 2, 0), 127) * 16384;
    float pfA = ps0[p1_off];
    float pfB = hasP2 ? ps0[p2_off] : 0.0f;
    uint4 cf1 = make_uint4(0u, 0u, 0u, 0u);
    uint4 cf2 = make_uint4(0u, 0u, 0u, 0u);
    uint4 hold = make_uint4(0u, 0u, 0u, 0u);
    uint4 cnew = make_uint4(0u, 0u, 0u, 0u);

    for (int x = x_lo - 2; x <= x_hi + 2; ++x) {
        int s0 = (x + 3) % 3;             // slot(x)
        int s1 = (x + 2) % 3;             // slot(x-1)
        int s2 = (x + 1) % 3;             // slot(x-2)
        bool xin = (x >= 0 && x < 128);

        // ---- W: commit prefetched phi(x) to P[s0] ----
        P[s0][tid] = (xin && p1_ok) ? pfA : 0.0f;
        if (hasP2) P[s0][p2i] = (xin && p2_ok) ? pfB : 0.0f;
        asm volatile("s_waitcnt lgkmcnt(0)" ::: "memory");
        __builtin_amdgcn_s_barrier();

        // ---- I: issue phi(x+1) prefetch (consumed next W) ----
        if (x < x_hi + 2) {
            const float* ps = pb + (size_t)min(max(x + 1, 0), 127) * 16384;
            pfA = ps[p1_off];
            if (hasP2) pfB = ps[p2_off];
        }

        // ---- B: compute S1(x-1) from coef regs + P ----
        if (x >= x_lo) {
            int k = x - 1;
            bool kin = ((unsigned)k < 128u);
            {
                float v = 0.0f;
                if (kin) {
                    const __half2* h = reinterpret_cast<const __half2*>(&cf1);
                    float2 a01 = __half22float2(h[0]);
                    float2 a23 = __half22float2(h[1]);
                    float2 a45 = __half22float2(h[2]);
                    float2 a67 = __half22float2(h[3]);
                    v = a01.x * P[s0][e1_p0]
                      + a01.y * P[s2][e1_p0]
                      + a23.x * P[s1][e1_p0 + PZD]
                      + a23.y * P[s1][e1_p0 - PZD]
                      + a45.x * P[s1][e1_p0 + 1]
                      + a45.y * P[s1][e1_p0 - 1]
                      + a67.x;
                }
                S[s1][e1_i] = v;
                cnew = cf1;
            }
            if (has2) {
                float v = 0.0f;
                if (kin && e2_ok) {
                    const __half2* h = reinterpret_cast<const __half2*>(&cf2);
                    float2 a01 = __half22float2(h[0]);
                    float2 a23 = __half22float2(h[1]);
                    float2 a45 = __half22float2(h[2]);
                    float2 a67 = __half22float2(h[3]);
                    v = a01.x * P[s0][e2_p0]
                      + a01.y * P[s2][e2_p0]
                      + a23.x * P[s1][e2_p0 + PZD]
                      + a23.y * P[s1][e2_p0 - PZD]
                      + a45.x * P[s1][e2_p0 + 1]
                      + a45.y * P[s1][e2_p0 - 1]
                      + a67.x;
                }
                S[s1][e2_i] = v;
            }
        }
        if (x >= x_lo - 1 && x <= x_hi + 1) {
            const uint4* cs = cb + (size_t)min(max(x, 0), 127) * 16384;
            cf1 = cs[e1_off];
            if (has2) cf2 = cs[e2_off];
        }
        asm volatile("s_waitcnt lgkmcnt(0)" ::: "memory");
        __builtin_amdgcn_s_barrier();

        // ---- C: output xo = x-2 from reg coef + S ----
        int xo = x - 2;
        if (xo >= x_lo) {
            const __half2* h = reinterpret_cast<const __half2*>(&hold);
            float2 a01 = __half22float2(h[0]);
            float2 a23 = __half22float2(h[1]);
            float2 a45 = __half22float2(h[2]);
            float2 a67 = __half22float2(h[3]);
            int j0 = e1_i;
            float out = a01.x * S[s1][j0]
                      + a01.y * S[s0][j0]
                      + a23.x * S[s2][j0 + RZ]
                      + a23.y * S[s2][j0 - RZ]
                      + a45.x * S[s2][j0 + 1]
                      + a45.y * S[s2][j0 - 1]
                      + a67.x;
            ob[(size_t)xo * 16384 + e1_off] = out;
        }
        hold = cnew;
    }
}

// ---------------- Jacobi sweep v3: 4 z-voxels/thread, fp16 coefs (verified) -
__global__ void jacobi_v3(const uint4* __restrict__ coef,
                          const float* __restrict__ pin,
                          float* __restrict__ pout)
{
    int tid = blockIdx.x * blockDim.x + threadIdx.x;   // 0 .. B*VOX/4-1
    size_t g4 = (size_t)tid * 4;
    int z4 = (int)(g4 & 127);          // 0,4,...,124
    int y  = (int)((g4 >> 7) & 127);
    int x  = (int)((g4 >> 14) & 127);

    float4 pcv = *reinterpret_cast<const float4*>(pin + g4);
    float4 z4v = make_float4(0.f, 0.f, 0.f, 0.f);
    float4 pxpv = (x < 127) ? *reinterpret_cast<const float4*>(pin + g4 + 16384) : z4v;
    float4 pxmv = (x > 0)   ? *reinterpret_cast<const float4*>(pin + g4 - 16384) : z4v;
    float4 pypv = (y < 127) ? *reinterpret_cast<const float4*>(pin + g4 + 128)   : z4v;
    float4 pymv = (y > 0)   ? *reinterpret_cast<const float4*>(pin + g4 - 128)   : z4v;
    float zpE = (z4 < 124) ? pin[g4 + 4] : 0.0f;
    float zmE = (z4 > 0)   ? pin[g4 - 1] : 0.0f;

    float pxp[4] = {pxpv.x, pxpv.y, pxpv.z, pxpv.w};
    float pxm[4] = {pxmv.x, pxmv.y, pxmv.z, pxmv.w};
    float pyp[4] = {pypv.x, pypv.y, pypv.z, pypv.w};
    float pym[4] = {pymv.x, pymv.y, pymv.z, pymv.w};
    float pzp[4] = {pcv.y, pcv.z, pcv.w, zpE};
    float pzm[4] = {zmE, pcv.x, pcv.y, pcv.z};

    float out[4];
#pragma unroll
    for (int j = 0; j < 4; ++j) {
        uint4 cu = coef[g4 + j];
        const __half2* h = reinterpret_cast<const __half2*>(&cu);
        float2 a01 = __half22float2(h[0]);
        float2 a23 = __half22float2(h[1]);
        float2 a45 = __half22float2(h[2]);
        float2 a67 = __half22float2(h[3]);
        out[j] = a01.x * pxp[j] + a01.y * pxm[j]
               + a23.x * pyp[j] + a23.y * pym[j]
               + a45.x * pzp[j] + a45.y * pzm[j]
               + a67.x;
    }
    *reinterpret_cast<float4*>(pout + g4) = make_float4(out[0], out[1], out[2], out[3]);
}

// ---------------- Jacobi sweep v2 (fallback path, verified) ----------------
__global__ void jacobi_v2(const float* __restrict__ eps,
                          const float* __restrict__ q,
                          const float* __restrict__ pin,
                          float* __restrict__ pout)
{
    int bxy = blockIdx.x;
    int b = bxy >> 14;
    int x = (bxy >> 7) & 127;
    int y = bxy & 127;
    int z = threadIdx.x;

    size_t sp = ((size_t)x * 128 + y) * 128 + z;
    size_t g  = (size_t)b * (size_t)VOX_ + sp;
    const float* E = eps + (size_t)b * 4 * (size_t)VOX_;

    float ex = E[sp];
    float ey = E[sp + (size_t)VOX_];
    float ez = E[sp + (size_t)VOX_ * 2];
    float ek = E[sp + (size_t)VOX_ * 3];
    float exm = (x > 0) ? E[sp - 16384]                 : EPS_OUT_C;
    float eym = (y > 0) ? E[sp + (size_t)VOX_ - 128]    : EPS_OUT_C;
    float ezm = (z > 0) ? E[sp + (size_t)VOX_ * 2 - 1]  : EPS_OUT_C;

    float lam = (ek - EPS_IN_C) / (EPS_OUT_C - EPS_IN_C);
    lam = fminf(fmaxf(lam, 0.0f), 1.0f);
    float denom = ex + exm + ey + eym + ez + ezm + KAPPA02_C * lam;

    float pxp = (x < 127) ? pin[g + 16384] : 0.0f;
    float pxm = (x > 0)   ? pin[g - 16384] : 0.0f;
    float pyp = (y < 127) ? pin[g + 128]   : 0.0f;
    float pym = (y > 0)   ? pin[g - 128]   : 0.0f;
    float pzp = (z < 127) ? pin[g + 1]     : 0.0f;
    float pzm = (z > 0)   ? pin[g - 1]     : 0.0f;

    float num = ex * pxp + exm * pxm + ey * pyp + eym * pym
              + ez * pzp + ezm * pzm + FOURPI_C * q[g];
    pout[g] = num / denom;
}

// ---------------- launch ----------------
extern "C" void kernel_launch(void* const* d_in, const int* in_sizes, int n_in,
                              void* d_out, int out_size, void* d_ws, size_t ws_size,
                              hipStream_t stream)
{
    const float* coords    = (const float*)d_in[0];
    const float* params    = (const float*)d_in[1];
    const int*   num_atoms = (const int*)d_in[2];

    float* q   = (float*)d_out;                       // [B][128^3]
    float* eps = q + (size_t)B_ * VOX_;               // [B][4][128^3]
    float* phi = eps + (size_t)B_ * 4 * VOX_;         // [B][128^3]

    hipMemsetAsync(q, 0, (size_t)B_ * VOX_ * sizeof(float), stream);

    scatter_q_kernel<<<(B_ * N_ + 255) / 256, 256, 0, stream>>>(coords, params, num_atoms, q);
    eps_gather_v3<<<B_ * 16 * 16, 512, 0, stream>>>(coords, params, num_atoms, eps);

    size_t coefBytes = (size_t)B_ * VOX_ * sizeof(uint4);              // 134 MB
    size_t need = coefBytes + (size_t)B_ * VOX_ * sizeof(float);       // +33.5 MB

    if (ws_size >= need) {
        uint4* coefA = (uint4*)d_ws;
        float* tmp   = (float*)((char*)d_ws + coefBytes);
        // sweep 1 folded into coef_pack4 (phi_0 == 0): phi1 -> phi
        coef_pack4<<<(int)(B_ * VOX_ / 4 / 256), 256, 0, stream>>>(eps, q, coefA, phi);
        const float* cur = phi;
        for (int it = 1; it <= 9; ++it) {           // 9 fused = sweeps 2..19
            float* dst = (it & 1) ? tmp : phi;      // it=9 (odd) -> tmp
            jacobi_f2p<<<B_ * 8 * 4 * 8, 512, 0, stream>>>(coefA, cur, dst);
            cur = dst;
        }
        // sweep 20: single v3 sweep tmp -> phi (d_out)
        jacobi_v3<<<(int)(B_ * VOX_ / 4 / 256), 256, 0, stream>>>(coefA, cur, phi);
    } else {
        hipMemsetAsync(phi, 0, (size_t)B_ * VOX_ * sizeof(float), stream);
        float* tmp = (float*)d_ws;
        int jb = B_ * 128 * 128;
        const float* cur = phi;
        for (int it = 1; it <= 20; ++it) {
            float* dst = (it & 1) ? tmp : phi;
            jacobi_v2<<<jb, 128, 0, stream>>>(eps, q, cur, dst);
            cur = dst;
        }
    }
}